// Round 11
// baseline (2046.189 us; speedup 1.0000x reference)
//
#include <hip/hip_runtime.h>
#include <math.h>

#define BATCH 8
#define NPTS 2048
#define KNN 20
#define BN_TOTAL (BATCH * NPTS)
#define EPSV 1e-5f
#define NT 16                 // j-tiles per row (2048/128)
#define NCAND (NT * KNN)      // 320 candidates per row

typedef __attribute__((ext_vector_type(8))) short short8v;   // 8 bf16
typedef __attribute__((ext_vector_type(4))) float floatx4;

// ---------------------------------------------------------------------------
// x2: per-row sum of squares
// ---------------------------------------------------------------------------
__global__ __launch_bounds__(256) void x2_kernel(const float* __restrict__ x, int C, int ldx,
                                                 float* __restrict__ x2) {
    int i = blockIdx.x * 256 + threadIdx.x;
    if (i >= BN_TOTAL) return;
    const float* xr = x + (size_t)i * ldx;
    float s = 0.f;
    if ((ldx & 3) == 0 && (C & 3) == 0) {
        const float4* xr4 = (const float4*)xr;
        for (int c = 0; c < (C >> 2); ++c) {
            float4 v = xr4[c];
            s = fmaf(v.x, v.x, s); s = fmaf(v.y, v.y, s);
            s = fmaf(v.z, v.z, s); s = fmaf(v.w, v.w, s);
        }
    } else {
        for (int c = 0; c < C; ++c) s = fmaf(xr[c], xr[c], s);
    }
    x2[i] = s;
}

// ---------------------------------------------------------------------------
// dtop20: round-4 dist GEMM (identical fp32 accumulation order) + per-(row,
// 128-col tile) EXACT top-20 extraction (guaranteed superset, no fallback).
// Extraction is the round-6 algorithm with loops restructured: iteration
// outer, all 8 rows (mi) inner, so 8 independent shfl chains overlap (ILP).
// cand[row][jt*20+slot] = (negdist, j), priority (val desc, j asc).
// ---------------------------------------------------------------------------
__global__ __launch_bounds__(256) void dtop20(const float* __restrict__ x,
                                              const float* __restrict__ x2,
                                              int C, int ldx,
                                              float2* __restrict__ cand) {
    __shared__ float As[16][132];
    __shared__ float Bs[16][132];
    int b = blockIdx.z;
    int jt = blockIdx.y;
    int i0 = blockIdx.x * 128, j0 = jt * 128;
    const float* xb = x + (size_t)b * NPTS * ldx;
    int tid = threadIdx.x;
    int tm = tid >> 4, tn = tid & 15;

    float acc[8][8] = {};
    int KT = (C + 15) >> 4;
    for (int kt = 0; kt < KT; ++kt) {
        int k0 = kt << 4;
#pragma unroll
        for (int s = tid; s < 512; s += 256) {
            int r = s >> 2, c4 = s & 3;
            int kk = k0 + c4 * 4;
            float va[4], vb[4];
            if (kk + 3 < C && (ldx & 3) == 0) {
                float4 a = *(const float4*)&xb[(size_t)(i0 + r) * ldx + kk];
                float4 bv = *(const float4*)&xb[(size_t)(j0 + r) * ldx + kk];
                va[0] = a.x; va[1] = a.y; va[2] = a.z; va[3] = a.w;
                vb[0] = bv.x; vb[1] = bv.y; vb[2] = bv.z; vb[3] = bv.w;
            } else {
#pragma unroll
                for (int u = 0; u < 4; ++u) {
                    int k = kk + u;
                    va[u] = (k < C) ? xb[(size_t)(i0 + r) * ldx + k] : 0.f;
                    vb[u] = (k < C) ? xb[(size_t)(j0 + r) * ldx + k] : 0.f;
                }
            }
#pragma unroll
            for (int u = 0; u < 4; ++u) {
                As[c4 * 4 + u][r] = va[u];
                Bs[c4 * 4 + u][r] = vb[u];
            }
        }
        __syncthreads();
#pragma unroll
        for (int k = 0; k < 16; ++k) {
            float4 a0 = *(const float4*)&As[k][tm * 8];
            float4 a1 = *(const float4*)&As[k][tm * 8 + 4];
            float4 c0 = *(const float4*)&Bs[k][tn * 8];
            float4 c1 = *(const float4*)&Bs[k][tn * 8 + 4];
            float av[8] = {a0.x, a0.y, a0.z, a0.w, a1.x, a1.y, a1.z, a1.w};
            float bv[8] = {c0.x, c0.y, c0.z, c0.w, c1.x, c1.y, c1.z, c1.w};
#pragma unroll
            for (int mi = 0; mi < 8; ++mi)
#pragma unroll
                for (int ni = 0; ni < 8; ++ni)
                    acc[mi][ni] = fmaf(av[mi], bv[ni], acc[mi][ni]);
        }
        __syncthreads();
    }

    // neg-dist transform (identical arithmetic/order to prior rounds)
    const float* x2b = x2 + (size_t)b * NPTS;
    float xj[8];
#pragma unroll
    for (int u = 0; u < 8; ++u) xj[u] = x2b[j0 + tn * 8 + u];
#pragma unroll
    for (int mi = 0; mi < 8; ++mi) {
        float xi = x2b[i0 + tm * 8 + mi];
#pragma unroll
        for (int ni = 0; ni < 8; ++ni)
            acc[mi][ni] = 2.f * acc[mi][ni] - xi - xj[ni];
    }

    // per-row lane maxima
    float lv[8]; int lj[8];
#pragma unroll
    for (int mi = 0; mi < 8; ++mi) {
        float v = acc[mi][0]; int u0 = 0;
#pragma unroll
        for (int u = 1; u < 8; ++u)
            if (acc[mi][u] > v) { v = acc[mi][u]; u0 = u; }
        lv[mi] = v; lj[mi] = j0 + tn * 8 + u0;
    }

    float w0v[8], w1v[8]; int w0j[8], w1j[8];
    // 20 exact argmax iterations; 8 rows' shfl chains run concurrently
#pragma unroll 1
    for (int it = 0; it < KNN; ++it) {
        float bv[8]; int bj[8];
#pragma unroll
        for (int mi = 0; mi < 8; ++mi) { bv[mi] = lv[mi]; bj[mi] = lj[mi]; }
#pragma unroll
        for (int d = 1; d < 16; d <<= 1) {
#pragma unroll
            for (int mi = 0; mi < 8; ++mi) {
                float ov = __shfl_xor(bv[mi], d);
                int oj = __shfl_xor(bj[mi], d);
                if (ov > bv[mi] || (ov == bv[mi] && oj < bj[mi])) { bv[mi] = ov; bj[mi] = oj; }
            }
        }
#pragma unroll
        for (int mi = 0; mi < 8; ++mi) {
            if (it < 16) { if (tn == it) { w0v[mi] = bv[mi]; w0j[mi] = bj[mi]; } }
            else if (tn == it - 16) { w1v[mi] = bv[mi]; w1j[mi] = bj[mi]; }
            if (bj[mi] == lj[mi]) {   // owner consumes winner, rescans its 8
                int r = lj[mi] - j0 - tn * 8;
#pragma unroll
                for (int u = 0; u < 8; ++u)
                    if (u == r) acc[mi][u] = -INFINITY;
                float v = acc[mi][0]; int u0 = 0;
#pragma unroll
                for (int u = 1; u < 8; ++u)
                    if (acc[mi][u] > v) { v = acc[mi][u]; u0 = u; }
                lv[mi] = v; lj[mi] = j0 + tn * 8 + u0;
            }
        }
    }

    // write the tile's 20 (val, j) per row
#pragma unroll
    for (int mi = 0; mi < 8; ++mi) {
        float2* cr = cand + ((size_t)(b << 11) + i0 + tm * 8 + mi) * NCAND + jt * KNN;
        cr[tn] = make_float2(w0v[mi], __int_as_float(w0j[mi]));
        if (tn < 4) cr[16 + tn] = make_float2(w1v[mi], __int_as_float(w1j[mi]));
    }
}

// ---------------------------------------------------------------------------
// ktop_merge: one wave per row; 320 candidates -> final top-20 indices.
// (round-6 kernel, verified)
// ---------------------------------------------------------------------------
__global__ __launch_bounds__(256) void ktop_merge(const float2* __restrict__ cand,
                                                  int* __restrict__ idx_out) {
    int lane = threadIdx.x & 63, w = threadIdx.x >> 6;
    int row = blockIdx.x * 4 + w;
    const float2* cr = cand + (size_t)row * NCAND;
    float v[5]; int j[5];
#pragma unroll
    for (int u = 0; u < 5; ++u) {
        float2 c = cr[lane + u * 64];
        v[u] = c.x; j[u] = __float_as_int(c.y);
    }
    float lv = v[0]; int lj = j[0];
#pragma unroll
    for (int u = 1; u < 5; ++u)
        if (v[u] > lv || (v[u] == lv && j[u] < lj)) { lv = v[u]; lj = j[u]; }

    int sel = 0;
#pragma unroll 1
    for (int it = 0; it < KNN; ++it) {
        float bv = lv; int bj = lj;
#pragma unroll
        for (int d = 1; d < 64; d <<= 1) {
            float ov = __shfl_xor(bv, d);
            int oj = __shfl_xor(bj, d);
            if (ov > bv || (ov == bv && oj < bj)) { bv = ov; bj = oj; }
        }
        if (lane == it) sel = bj;
        if (bj == lj) {          // owner invalidates its copy
#pragma unroll
            for (int u = 0; u < 5; ++u)
                if (j[u] == bj) { v[u] = -INFINITY; j[u] = 0x7fffffff; }
            lv = v[0]; lj = j[0];
#pragma unroll
            for (int u = 1; u < 5; ++u)
                if (v[u] > lv || (v[u] == lv && j[u] < lj)) { lv = v[u]; lj = j[u]; }
        }
    }
    if (lane < KNN) idx_out[(size_t)row * KNN + lane] = sel;
}

// ---------------------------------------------------------------------------
// pq_gemm: PQ[bn][0..O)=x.Wp^T, PQ[bn][O..2O)=x.Wq^T as one GEMM (N=2O).
// ---------------------------------------------------------------------------
__global__ __launch_bounds__(256) void pq_gemm(const float* __restrict__ X, int C, int ldx,
                                               const float* __restrict__ W, int O,
                                               float* __restrict__ PQ) {
    __shared__ float As[32][68];
    __shared__ float Bs[32][68];
    int i0 = blockIdx.x * 64, j0 = blockIdx.y * 64;
    int tid = threadIdx.x;
    int tm = tid >> 4, tn = tid & 15;
    int N2 = 2 * O;

    float acc[4][4] = {};
    int KT = (C + 31) >> 5;
    for (int kt = 0; kt < KT; ++kt) {
        int k0 = kt << 5;
        for (int e = tid; e < 2048; e += 256) {
            int m = e >> 5, k = e & 31;
            int kk = k0 + k;
            As[k][m] = (kk < C) ? X[(size_t)(i0 + m) * ldx + kk] : 0.f;
            int o = j0 + m;
            float wv = 0.f;
            if (kk < C)
                wv = (o < O) ? W[(size_t)o * 2 * C + kk] : W[(size_t)(o - O) * 2 * C + C + kk];
            Bs[k][m] = wv;
        }
        __syncthreads();
#pragma unroll
        for (int k = 0; k < 32; ++k) {
            float4 a = *(const float4*)&As[k][tm * 4];
            float4 bb = *(const float4*)&Bs[k][tn * 4];
            float av[4] = {a.x, a.y, a.z, a.w};
            float bv[4] = {bb.x, bb.y, bb.z, bb.w};
#pragma unroll
            for (int mi = 0; mi < 4; ++mi)
#pragma unroll
                for (int ni = 0; ni < 4; ++ni)
                    acc[mi][ni] = fmaf(av[mi], bv[ni], acc[mi][ni]);
        }
        __syncthreads();
    }
#pragma unroll
    for (int mi = 0; mi < 4; ++mi) {
        float4 o;
        o.x = acc[mi][0]; o.y = acc[mi][1]; o.z = acc[mi][2]; o.w = acc[mi][3];
        *(float4*)&PQ[(size_t)(i0 + tm * 4 + mi) * N2 + j0 + tn * 4] = o;
    }
}

// ---------------------------------------------------------------------------
// gather-max + BN + LeakyReLU epilogue. 256/O rows per block, all lanes busy.
// ---------------------------------------------------------------------------
__global__ __launch_bounds__(256) void gmax_kernel(const float* __restrict__ PQ,
                                                   const int* __restrict__ idx, int O, int oshift,
                                                   const float* __restrict__ gamma,
                                                   const float* __restrict__ beta,
                                                   float* __restrict__ out, int ldo) {
    __shared__ int s_idx[4][KNN];
    int rpb = 256 >> oshift;                 // O in {64,128,256}
    int lr = threadIdx.x >> oshift;
    int o = threadIdx.x & (O - 1);
    int bn = blockIdx.x * rpb + lr;
    int b = bn >> 11;
    if (o < KNN) s_idx[lr][o] = idx[bn * KNN + o];
    __syncthreads();
    const float inv = 1.0f / sqrtf(1.0f + EPSV);
    int N2 = 2 * O;
    size_t brow = (size_t)(b << 11);
    float mx = -INFINITY, mn = INFINITY;
#pragma unroll
    for (int k = 0; k < KNN; ++k) {
        float v = PQ[(brow + s_idx[lr][k]) * N2 + o];
        mx = fmaxf(mx, v);
        mn = fminf(mn, v);
    }
    float pn = PQ[(size_t)bn * N2 + o];
    float qn = PQ[(size_t)bn * N2 + O + o];
    float sc = gamma[o] * inv;
    float m = (sc >= 0.f) ? mx : mn;
    float z = sc * (m - pn + qn) + beta[o];
    out[(size_t)bn * ldo + o] = (z >= 0.f) ? z : 0.2f * z;
}

// ---------------------------------------------------------------------------
// split_bf16: x -> (hi, lo) bf16 pair, RNE.
// ---------------------------------------------------------------------------
__device__ __forceinline__ unsigned short bf16_rne(float x) {
    union { float f; unsigned u; } cv; cv.f = x;
    unsigned r = (cv.u + 0x7fffu + ((cv.u >> 16) & 1u)) >> 16;
    return (unsigned short)r;
}
__global__ __launch_bounds__(256) void split_bf16_kernel(const float* __restrict__ in, int n4,
                                                         unsigned short* __restrict__ hi,
                                                         unsigned short* __restrict__ lo) {
    int i = blockIdx.x * 256 + threadIdx.x;
    if (i >= n4) return;
    float4 v = ((const float4*)in)[i];
    float vv[4] = {v.x, v.y, v.z, v.w};
    ushort4 h, l;
    unsigned short hh[4], ll[4];
#pragma unroll
    for (int u = 0; u < 4; ++u) {
        unsigned short hb = bf16_rne(vv[u]);
        union { unsigned u32; float f; } hf; hf.u32 = ((unsigned)hb) << 16;
        hh[u] = hb;
        ll[u] = bf16_rne(vv[u] - hf.f);
    }
    h.x = hh[0]; h.y = hh[1]; h.z = hh[2]; h.w = hh[3];
    l.x = ll[0]; l.y = ll[1]; l.z = ll[2]; l.w = ll[3];
    *(ushort4*)(hi + (size_t)i * 4) = h;
    *(ushort4*)(lo + (size_t)i * 4) = l;
}

// ---------------------------------------------------------------------------
// final MFMA GEMM: feat = lrelu(bn(X @ W5^T)) with split-bf16 (3 K-segments),
// fused partial max/sum over the 128 n-rows. 128x128 tile, BK=32, 4 waves.
// ---------------------------------------------------------------------------
__global__ __launch_bounds__(256) void final_mfma(const unsigned short* __restrict__ Xhi,
                                                  const unsigned short* __restrict__ Xlo,
                                                  const unsigned short* __restrict__ Whi,
                                                  const unsigned short* __restrict__ Wlo,
                                                  const float* __restrict__ g5,
                                                  const float* __restrict__ b5,
                                                  float* __restrict__ part) {
    __shared__ __align__(16) char As[128 * 64];
    __shared__ __align__(16) char Bs[128 * 64];
    __shared__ float sredM[2][128];
    __shared__ float sredS[2][128];

    int tid = threadIdx.x;
    int i0 = blockIdx.x * 128;
    int j0 = blockIdx.y * 128;
    int lane = tid & 63, w = tid >> 6;
    int wr = w >> 1, wc = w & 1;

    int rowA = tid >> 2, q = tid & 3;
    auto swz = [](int row, int qq) { return (row * 64 + qq * 16) ^ ((row & 7) << 4); };
    int wa0 = swz(rowA, q), wa1 = swz(rowA + 64, q);

    int fr = lane & 15, slot = lane >> 4;
    int aoff[4], boff[4];
#pragma unroll
    for (int m = 0; m < 4; ++m) {
        int ra = wr * 64 + m * 16 + fr;
        aoff[m] = (ra * 64 + slot * 16) ^ ((ra & 7) << 4);
        int rb = wc * 64 + m * 16 + fr;
        boff[m] = (rb * 64 + slot * 16) ^ ((rb & 7) << 4);
    }

    floatx4 acc[4][4];
#pragma unroll
    for (int m = 0; m < 4; ++m)
#pragma unroll
        for (int n = 0; n < 4; ++n)
            acc[m][n] = (floatx4){0.f, 0.f, 0.f, 0.f};

    uint4 ra0, ra1, rb0, rb1;
    auto prefetch = [&](int it) {
        int seg = it >> 4;
        int kk = (it & 15) * 32;
        const unsigned short* Ab = ((seg < 2) ? Xhi : Xlo) + (size_t)i0 * 512 + kk + q * 8;
        const unsigned short* Bb = ((seg == 1) ? Wlo : Whi) + (size_t)j0 * 512 + kk + q * 8;
        ra0 = *(const uint4*)(Ab + (size_t)rowA * 512);
        ra1 = *(const uint4*)(Ab + (size_t)(rowA + 64) * 512);
        rb0 = *(const uint4*)(Bb + (size_t)rowA * 512);
        rb1 = *(const uint4*)(Bb + (size_t)(rowA + 64) * 512);
    };

    prefetch(0);
    for (int it = 0; it < 48; ++it) {
        __syncthreads();
        *(uint4*)(As + wa0) = ra0;
        *(uint4*)(As + wa1) = ra1;
        *(uint4*)(Bs + wa0) = rb0;
        *(uint4*)(Bs + wa1) = rb1;
        __syncthreads();
        if (it < 47) prefetch(it + 1);
        short8v af[4], bf[4];
#pragma unroll
        for (int m = 0; m < 4; ++m) af[m] = *(const short8v*)(As + aoff[m]);
#pragma unroll
        for (int n = 0; n < 4; ++n) bf[n] = *(const short8v*)(Bs + boff[n]);
#pragma unroll
        for (int m = 0; m < 4; ++m)
#pragma unroll
            for (int n = 0; n < 4; ++n)
                acc[m][n] = __builtin_amdgcn_mfma_f32_16x16x32_bf16(af[m], bf[n], acc[m][n], 0, 0, 0);
    }

    const float inv = 1.0f / sqrtf(1.0f + EPSV);
#pragma unroll
    for (int n = 0; n < 4; ++n) {
        int o = j0 + wc * 64 + n * 16 + fr;
        float sc = g5[o] * inv;
        float bi = b5[o];
        float mx = -INFINITY, sm = 0.f;
#pragma unroll
        for (int m = 0; m < 4; ++m)
#pragma unroll
            for (int r = 0; r < 4; ++r) {
                float z = fmaf(sc, acc[m][n][r], bi);
                z = (z >= 0.f) ? z : 0.2f * z;
                mx = fmaxf(mx, z);
                sm += z;
            }
#pragma unroll
        for (int d = 16; d < 64; d <<= 1) {
            mx = fmaxf(mx, __shfl_xor(mx, d));
            sm += __shfl_xor(sm, d);
        }
        if (slot == 0) {
            sredM[wr][wc * 64 + n * 16 + fr] = mx;
            sredS[wr][wc * 64 + n * 16 + fr] = sm;
        }
    }
    __syncthreads();
    if (tid < 128) {
        float m = fmaxf(sredM[0][tid], sredM[1][tid]);
        float s = sredS[0][tid] + sredS[1][tid];
        int b = i0 >> 11, nt = (i0 >> 7) & 15;
        size_t base = (size_t)((b * 16 + nt) * 2) * 1024 + j0 + tid;
        part[base] = m;
        part[base + 1024] = s;
    }
}

__global__ __launch_bounds__(256) void freduce_kernel(const float* __restrict__ part,
                                                      float* __restrict__ out) {
    int t = blockIdx.x * 256 + threadIdx.x;
    if (t >= 8 * 1024) return;
    int b = t >> 10, o = t & 1023;
    float m = -INFINITY, s = 0.f;
#pragma unroll
    for (int nt = 0; nt < 16; ++nt) {
        size_t base = (size_t)((b * 16 + nt) * 2) * 1024 + o;
        m = fmaxf(m, part[base]);
        s += part[base + 1024];
    }
    out[b * 2048 + o] = m;
    out[b * 2048 + 1024 + o] = s * (1.0f / 2048.0f);
}

// ---------------------------------------------------------------------------
extern "C" void kernel_launch(void* const* d_in, const int* in_sizes, int n_in,
                              void* d_out, int out_size, void* d_ws, size_t ws_size,
                              hipStream_t stream) {
    const float* points = (const float*)d_in[0];
    const float* W1 = (const float*)d_in[1];
    const float* W2 = (const float*)d_in[2];
    const float* W3 = (const float*)d_in[3];
    const float* W4 = (const float*)d_in[4];
    const float* W5 = (const float*)d_in[5];
    const float* g1 = (const float*)d_in[6];
    const float* b1 = (const float*)d_in[7];
    const float* g2 = (const float*)d_in[8];
    const float* b2 = (const float*)d_in[9];
    const float* g3 = (const float*)d_in[10];
    const float* b3 = (const float*)d_in[11];
    const float* g4 = (const float*)d_in[12];
    const float* b4 = (const float*)d_in[13];
    const float* g5 = (const float*)d_in[14];
    const float* b5 = (const float*)d_in[15];
    float* out = (float*)d_out;

    const size_t f_xcat = (size_t)BN_TOTAL * 512;            // 8.4M floats
    const size_t f_w5 = (size_t)1024 * 512;
    const size_t f_union = (size_t)BN_TOTAL * NCAND * 2;     // cand 10.5M floats
    const size_t f_x2 = BN_TOTAL;
    const size_t f_idx = (size_t)BN_TOTAL * KNN;             // ints
    const size_t f_part = (size_t)8 * 16 * 2 * 1024;

    float* xcat = (float*)d_ws;
    float* U = xcat + f_xcat;               // union: cand | PQ | bf16 buffers
    float* SPQ = U;
    float2* cand = (float2*)U;
    unsigned short* Xhi = (unsigned short*)U;
    unsigned short* Xlo = Xhi + f_xcat;
    unsigned short* Whi = Xlo + f_xcat;
    unsigned short* Wlo = Whi + f_w5;
    float* x2 = U + f_union;
    int* idx = (int*)(x2 + f_x2);
    float* part = (float*)(idx + f_idx);

    auto layer = [&](const float* xin, int C, int ldx, const float* W, int O, int oshift,
                     const float* ga, const float* be, float* xout) {
        x2_kernel<<<(BN_TOTAL + 255) / 256, 256, 0, stream>>>(xin, C, ldx, x2);
        dtop20<<<dim3(16, NT, 8), 256, 0, stream>>>(xin, x2, C, ldx, cand);
        ktop_merge<<<BN_TOTAL / 4, 256, 0, stream>>>(cand, idx);
        pq_gemm<<<dim3(BN_TOTAL / 64, (2 * O) / 64), 256, 0, stream>>>(xin, C, ldx, W, O, SPQ);
        int rpb = 256 >> oshift;
        gmax_kernel<<<BN_TOTAL / rpb, 256, 0, stream>>>(SPQ, idx, O, oshift, ga, be, xout, 512);
    };

    layer(points,     3,   3,   W1, 64,  6, g1, b1, xcat + 0);
    layer(xcat + 0,   64,  512, W2, 64,  6, g2, b2, xcat + 64);
    layer(xcat + 64,  64,  512, W3, 128, 7, g3, b3, xcat + 128);
    layer(xcat + 128, 128, 512, W4, 256, 8, g4, b4, xcat + 256);

    split_bf16_kernel<<<(int)((f_xcat / 4 + 255) / 256), 256, 0, stream>>>(xcat, (int)(f_xcat / 4), Xhi, Xlo);
    split_bf16_kernel<<<(int)((f_w5 / 4 + 255) / 256), 256, 0, stream>>>(W5, (int)(f_w5 / 4), Whi, Wlo);
    final_mfma<<<dim3(BN_TOTAL / 128, 1024 / 128), 256, 0, stream>>>(Xhi, Xlo, Whi, Wlo, g5, b5, part);
    freduce_kernel<<<(8 * 1024 + 255) / 256, 256, 0, stream>>>(part, out);
}

// Round 12
// 970.671 us; speedup vs baseline: 2.1080x; 2.1080x over previous
//
#include <hip/hip_runtime.h>
#include <math.h>

#define BATCH 8
#define NPTS 2048
#define KNN 20
#define BN_TOTAL (BATCH * NPTS)
#define EPSV 1e-5f

typedef __attribute__((ext_vector_type(8))) short short8v;   // 8 bf16
typedef __attribute__((ext_vector_type(4))) float floatx4;

// ---------------------------------------------------------------------------
// x2: per-row sum of squares
// ---------------------------------------------------------------------------
__global__ __launch_bounds__(256) void x2_kernel(const float* __restrict__ x, int C, int ldx,
                                                 float* __restrict__ x2) {
    int i = blockIdx.x * 256 + threadIdx.x;
    if (i >= BN_TOTAL) return;
    const float* xr = x + (size_t)i * ldx;
    float s = 0.f;
    if ((ldx & 3) == 0 && (C & 3) == 0) {
        const float4* xr4 = (const float4*)xr;
        for (int c = 0; c < (C >> 2); ++c) {
            float4 v = xr4[c];
            s = fmaf(v.x, v.x, s); s = fmaf(v.y, v.y, s);
            s = fmaf(v.z, v.z, s); s = fmaf(v.w, v.w, s);
        }
    } else {
        for (int c = 0; c < C; ++c) s = fmaf(xr[c], xr[c], s);
    }
    x2[i] = s;
}

// ---------------------------------------------------------------------------
// dist: tiled GEMM, neg_dist S[z*2048+i][j] = 2*dot(xi,xj) - x2i - x2j.
// 128x128 tile, BK=16, 256 thr, 8x8 micro-tile. (verbatim round-4 kernel)
// ---------------------------------------------------------------------------
__global__ __launch_bounds__(256) void dist_kernel(const float* __restrict__ x,
                                                   const float* __restrict__ x2,
                                                   int C, int ldx, int b0,
                                                   float* __restrict__ S) {
    __shared__ float As[16][132];
    __shared__ float Bs[16][132];
    int z = blockIdx.z;
    int b = b0 + z;
    int i0 = blockIdx.x * 128, j0 = blockIdx.y * 128;
    const float* xb = x + (size_t)b * NPTS * ldx;
    int tid = threadIdx.x;
    int tm = tid >> 4, tn = tid & 15;

    float acc[8][8] = {};
    int KT = (C + 15) >> 4;
    for (int kt = 0; kt < KT; ++kt) {
        int k0 = kt << 4;
#pragma unroll
        for (int s = tid; s < 512; s += 256) {
            int r = s >> 2, c4 = s & 3;
            int kk = k0 + c4 * 4;
            float va[4], vb[4];
            if (kk + 3 < C && (ldx & 3) == 0) {
                float4 a = *(const float4*)&xb[(size_t)(i0 + r) * ldx + kk];
                float4 bv = *(const float4*)&xb[(size_t)(j0 + r) * ldx + kk];
                va[0] = a.x; va[1] = a.y; va[2] = a.z; va[3] = a.w;
                vb[0] = bv.x; vb[1] = bv.y; vb[2] = bv.z; vb[3] = bv.w;
            } else {
#pragma unroll
                for (int u = 0; u < 4; ++u) {
                    int k = kk + u;
                    va[u] = (k < C) ? xb[(size_t)(i0 + r) * ldx + k] : 0.f;
                    vb[u] = (k < C) ? xb[(size_t)(j0 + r) * ldx + k] : 0.f;
                }
            }
#pragma unroll
            for (int u = 0; u < 4; ++u) {
                As[c4 * 4 + u][r] = va[u];
                Bs[c4 * 4 + u][r] = vb[u];
            }
        }
        __syncthreads();
#pragma unroll
        for (int k = 0; k < 16; ++k) {
            float4 a0 = *(const float4*)&As[k][tm * 8];
            float4 a1 = *(const float4*)&As[k][tm * 8 + 4];
            float4 c0 = *(const float4*)&Bs[k][tn * 8];
            float4 c1 = *(const float4*)&Bs[k][tn * 8 + 4];
            float av[8] = {a0.x, a0.y, a0.z, a0.w, a1.x, a1.y, a1.z, a1.w};
            float bv[8] = {c0.x, c0.y, c0.z, c0.w, c1.x, c1.y, c1.z, c1.w};
#pragma unroll
            for (int mi = 0; mi < 8; ++mi)
#pragma unroll
                for (int ni = 0; ni < 8; ++ni)
                    acc[mi][ni] = fmaf(av[mi], bv[ni], acc[mi][ni]);
        }
        __syncthreads();
    }

    const float* x2b = x2 + (size_t)b * NPTS;
    float xj[8];
#pragma unroll
    for (int u = 0; u < 8; ++u) xj[u] = x2b[j0 + tn * 8 + u];
#pragma unroll
    for (int mi = 0; mi < 8; ++mi) {
        float xi = x2b[i0 + tm * 8 + mi];
        float4 o0, o1;
        o0.x = 2.f * acc[mi][0] - xi - xj[0];
        o0.y = 2.f * acc[mi][1] - xi - xj[1];
        o0.z = 2.f * acc[mi][2] - xi - xj[2];
        o0.w = 2.f * acc[mi][3] - xi - xj[3];
        o1.x = 2.f * acc[mi][4] - xi - xj[4];
        o1.y = 2.f * acc[mi][5] - xi - xj[5];
        o1.z = 2.f * acc[mi][6] - xi - xj[6];
        o1.w = 2.f * acc[mi][7] - xi - xj[7];
        size_t rowp = ((size_t)z * NPTS + i0 + tm * 8 + mi) * NPTS + j0 + tn * 8;
        *(float4*)&S[rowp] = o0;
        *(float4*)&S[rowp + 4] = o1;
    }
}

// ---------------------------------------------------------------------------
// topk: one wave per row; 32 values/lane in registers; 20 shfl-argmax iters.
// (verbatim round-4 kernel)
// ---------------------------------------------------------------------------
__global__ __launch_bounds__(256) void topk_kernel(const float* __restrict__ S, int b0,
                                                   int* __restrict__ idx_out) {
    int lane = threadIdx.x & 63, w = threadIdx.x >> 6;
    int row = blockIdx.x * 4 + w;
    const float4* S4 = (const float4*)(S + (size_t)row * NPTS);

    float v[32];
    float lm = -INFINITY; int li = 0;
#pragma unroll
    for (int r4 = 0; r4 < 8; ++r4) {
        float4 f = S4[lane * 8 + r4];
        v[r4 * 4 + 0] = f.x; v[r4 * 4 + 1] = f.y;
        v[r4 * 4 + 2] = f.z; v[r4 * 4 + 3] = f.w;
    }
#pragma unroll
    for (int q = 0; q < 32; ++q)
        if (v[q] > lm) { lm = v[q]; li = q; }

    int sel = 0;
#pragma unroll 1
    for (int it = 0; it < KNN; ++it) {
        float bv = lm;
        int bi = (lane << 5) | li;
#pragma unroll
        for (int d = 1; d < 64; d <<= 1) {
            float ov = __shfl_xor(bv, d);
            int oi = __shfl_xor(bi, d);
            if (ov > bv || (ov == bv && oi < bi)) { bv = ov; bi = oi; }
        }
        if (lane == it) sel = bi;
        if ((bi >> 5) == lane) {
            int r = bi & 31;
#pragma unroll
            for (int q = 0; q < 32; ++q)
                if (q == r) v[q] = -INFINITY;
            lm = -INFINITY; li = 0;
#pragma unroll
            for (int q = 0; q < 32; ++q)
                if (v[q] > lm) { lm = v[q]; li = q; }
        }
    }
    int z = row >> 11, i = row & 2047;
    int bn = (b0 + z) * NPTS + i;
    if (lane < KNN) idx_out[bn * KNN + lane] = sel;
}

// ---------------------------------------------------------------------------
// pq_gemm: PQ[bn][0..O)=x.Wp^T, PQ[bn][O..2O)=x.Wq^T as one GEMM (N=2O).
// ---------------------------------------------------------------------------
__global__ __launch_bounds__(256) void pq_gemm(const float* __restrict__ X, int C, int ldx,
                                               const float* __restrict__ W, int O,
                                               float* __restrict__ PQ) {
    __shared__ float As[32][68];
    __shared__ float Bs[32][68];
    int i0 = blockIdx.x * 64, j0 = blockIdx.y * 64;
    int tid = threadIdx.x;
    int tm = tid >> 4, tn = tid & 15;
    int N2 = 2 * O;

    float acc[4][4] = {};
    int KT = (C + 31) >> 5;
    for (int kt = 0; kt < KT; ++kt) {
        int k0 = kt << 5;
        for (int e = tid; e < 2048; e += 256) {
            int m = e >> 5, k = e & 31;
            int kk = k0 + k;
            As[k][m] = (kk < C) ? X[(size_t)(i0 + m) * ldx + kk] : 0.f;
            int o = j0 + m;
            float wv = 0.f;
            if (kk < C)
                wv = (o < O) ? W[(size_t)o * 2 * C + kk] : W[(size_t)(o - O) * 2 * C + C + kk];
            Bs[k][m] = wv;
        }
        __syncthreads();
#pragma unroll
        for (int k = 0; k < 32; ++k) {
            float4 a = *(const float4*)&As[k][tm * 4];
            float4 bb = *(const float4*)&Bs[k][tn * 4];
            float av[4] = {a.x, a.y, a.z, a.w};
            float bv[4] = {bb.x, bb.y, bb.z, bb.w};
#pragma unroll
            for (int mi = 0; mi < 4; ++mi)
#pragma unroll
                for (int ni = 0; ni < 4; ++ni)
                    acc[mi][ni] = fmaf(av[mi], bv[ni], acc[mi][ni]);
        }
        __syncthreads();
    }
#pragma unroll
    for (int mi = 0; mi < 4; ++mi) {
        float4 o;
        o.x = acc[mi][0]; o.y = acc[mi][1]; o.z = acc[mi][2]; o.w = acc[mi][3];
        *(float4*)&PQ[(size_t)(i0 + tm * 4 + mi) * N2 + j0 + tn * 4] = o;
    }
}

// ---------------------------------------------------------------------------
// gather-max + BN + LeakyReLU epilogue. 256/O rows per block, all lanes busy.
// ---------------------------------------------------------------------------
__global__ __launch_bounds__(256) void gmax_kernel(const float* __restrict__ PQ,
                                                   const int* __restrict__ idx, int O, int oshift,
                                                   const float* __restrict__ gamma,
                                                   const float* __restrict__ beta,
                                                   float* __restrict__ out, int ldo) {
    __shared__ int s_idx[4][KNN];
    int rpb = 256 >> oshift;                 // O in {64,128,256}
    int lr = threadIdx.x >> oshift;
    int o = threadIdx.x & (O - 1);
    int bn = blockIdx.x * rpb + lr;
    int b = bn >> 11;
    if (o < KNN) s_idx[lr][o] = idx[bn * KNN + o];
    __syncthreads();
    const float inv = 1.0f / sqrtf(1.0f + EPSV);
    int N2 = 2 * O;
    size_t brow = (size_t)(b << 11);
    float mx = -INFINITY, mn = INFINITY;
#pragma unroll
    for (int k = 0; k < KNN; ++k) {
        float v = PQ[(brow + s_idx[lr][k]) * N2 + o];
        mx = fmaxf(mx, v);
        mn = fminf(mn, v);
    }
    float pn = PQ[(size_t)bn * N2 + o];
    float qn = PQ[(size_t)bn * N2 + O + o];
    float sc = gamma[o] * inv;
    float m = (sc >= 0.f) ? mx : mn;
    float z = sc * (m - pn + qn) + beta[o];
    out[(size_t)bn * ldo + o] = (z >= 0.f) ? z : 0.2f * z;
}

// ---------------------------------------------------------------------------
// split_bf16: x -> (hi, lo) bf16 pair, RNE. hi+lo reproduces x to ~2^-16 rel.
// ---------------------------------------------------------------------------
__device__ __forceinline__ unsigned short bf16_rne(float x) {
    union { float f; unsigned u; } cv; cv.f = x;
    unsigned r = (cv.u + 0x7fffu + ((cv.u >> 16) & 1u)) >> 16;
    return (unsigned short)r;
}
__global__ __launch_bounds__(256) void split_bf16_kernel(const float* __restrict__ in, int n4,
                                                         unsigned short* __restrict__ hi,
                                                         unsigned short* __restrict__ lo) {
    int i = blockIdx.x * 256 + threadIdx.x;
    if (i >= n4) return;
    float4 v = ((const float4*)in)[i];
    float vv[4] = {v.x, v.y, v.z, v.w};
    ushort4 h, l;
    unsigned short hh[4], ll[4];
#pragma unroll
    for (int u = 0; u < 4; ++u) {
        unsigned short hb = bf16_rne(vv[u]);
        union { unsigned u32; float f; } hf; hf.u32 = ((unsigned)hb) << 16;
        hh[u] = hb;
        ll[u] = bf16_rne(vv[u] - hf.f);
    }
    h.x = hh[0]; h.y = hh[1]; h.z = hh[2]; h.w = hh[3];
    l.x = ll[0]; l.y = ll[1]; l.z = ll[2]; l.w = ll[3];
    *(ushort4*)(hi + (size_t)i * 4) = h;
    *(ushort4*)(lo + (size_t)i * 4) = l;
}

// ---------------------------------------------------------------------------
// final MFMA GEMM: feat = lrelu(bn(X @ W5^T)) with split-bf16 (3 K-segments:
// Xhi.Whi + Xhi.Wlo + Xlo.Whi), fused partial max/sum over the 128 n-rows.
// 128x128 tile, BK=32, 4 waves (2x2), each wave 4x4 frags of 16x16x32.
// LDS row stride 80B (was 64B+XOR): bank = (20*row + 4*slot) mod 32 ->
// 2-way max on both ds_write_b128 and ds_read_b128 (free per m136).
// ---------------------------------------------------------------------------
#define LSTR 80
__global__ __launch_bounds__(256) void final_mfma(const unsigned short* __restrict__ Xhi,
                                                  const unsigned short* __restrict__ Xlo,
                                                  const unsigned short* __restrict__ Whi,
                                                  const unsigned short* __restrict__ Wlo,
                                                  const float* __restrict__ g5,
                                                  const float* __restrict__ b5,
                                                  float* __restrict__ part) {
    __shared__ __align__(16) char As[128 * LSTR];   // [row][32 bf16], stride 80B
    __shared__ __align__(16) char Bs[128 * LSTR];
    __shared__ float sredM[2][128];
    __shared__ float sredS[2][128];

    int tid = threadIdx.x;
    int i0 = blockIdx.x * 128;
    int j0 = blockIdx.y * 128;
    int lane = tid & 63, w = tid >> 6;
    int wr = w >> 1, wc = w & 1;

    // staging assignment: thread -> (row, 16B-quarter), two rows apart 64
    int rowA = tid >> 2, q = tid & 3;
    int wa0 = rowA * LSTR + q * 16;
    int wa1 = (rowA + 64) * LSTR + q * 16;

    // fragment LDS byte offsets (same stride-80 layout)
    int fr = lane & 15, slot = lane >> 4;
    int aoff[4], boff[4];
#pragma unroll
    for (int m = 0; m < 4; ++m) {
        int ra = wr * 64 + m * 16 + fr;
        aoff[m] = ra * LSTR + slot * 16;
        int rb = wc * 64 + m * 16 + fr;
        boff[m] = rb * LSTR + slot * 16;
    }

    floatx4 acc[4][4];
#pragma unroll
    for (int m = 0; m < 4; ++m)
#pragma unroll
        for (int n = 0; n < 4; ++n)
            acc[m][n] = (floatx4){0.f, 0.f, 0.f, 0.f};

    uint4 ra0, ra1, rb0, rb1;
    auto prefetch = [&](int it) {
        int seg = it >> 4;
        int kk = (it & 15) * 32;
        const unsigned short* Ab = ((seg < 2) ? Xhi : Xlo) + (size_t)i0 * 512 + kk + q * 8;
        const unsigned short* Bb = ((seg == 1) ? Wlo : Whi) + (size_t)j0 * 512 + kk + q * 8;
        ra0 = *(const uint4*)(Ab + (size_t)rowA * 512);
        ra1 = *(const uint4*)(Ab + (size_t)(rowA + 64) * 512);
        rb0 = *(const uint4*)(Bb + (size_t)rowA * 512);
        rb1 = *(const uint4*)(Bb + (size_t)(rowA + 64) * 512);
    };

    prefetch(0);
    for (int it = 0; it < 48; ++it) {
        __syncthreads();
        *(uint4*)(As + wa0) = ra0;
        *(uint4*)(As + wa1) = ra1;
        *(uint4*)(Bs + wa0) = rb0;
        *(uint4*)(Bs + wa1) = rb1;
        __syncthreads();
        if (it < 47) prefetch(it + 1);
        short8v af[4], bf[4];
#pragma unroll
        for (int m = 0; m < 4; ++m) af[m] = *(const short8v*)(As + aoff[m]);
#pragma unroll
        for (int n = 0; n < 4; ++n) bf[n] = *(const short8v*)(Bs + boff[n]);
#pragma unroll
        for (int m = 0; m < 4; ++m)
#pragma unroll
            for (int n = 0; n < 4; ++n)
                acc[m][n] = __builtin_amdgcn_mfma_f32_16x16x32_bf16(af[m], bf[n], acc[m][n], 0, 0, 0);
    }

    // epilogue: BN + lrelu + per-column (max,sum) over this block's 128 rows
    const float inv = 1.0f / sqrtf(1.0f + EPSV);
#pragma unroll
    for (int n = 0; n < 4; ++n) {
        int o = j0 + wc * 64 + n * 16 + fr;
        float sc = g5[o] * inv;
        float bi = b5[o];
        float mx = -INFINITY, sm = 0.f;
#pragma unroll
        for (int m = 0; m < 4; ++m)
#pragma unroll
            for (int r = 0; r < 4; ++r) {
                float z = fmaf(sc, acc[m][n][r], bi);
                z = (z >= 0.f) ? z : 0.2f * z;
                mx = fmaxf(mx, z);
                sm += z;
            }
#pragma unroll
        for (int d = 16; d < 64; d <<= 1) {
            mx = fmaxf(mx, __shfl_xor(mx, d));
            sm += __shfl_xor(sm, d);
        }
        if (slot == 0) {
            sredM[wr][wc * 64 + n * 16 + fr] = mx;
            sredS[wr][wc * 64 + n * 16 + fr] = sm;
        }
    }
    __syncthreads();
    if (tid < 128) {
        float m = fmaxf(sredM[0][tid], sredM[1][tid]);
        float s = sredS[0][tid] + sredS[1][tid];
        int b = i0 >> 11, nt = (i0 >> 7) & 15;
        size_t base = (size_t)((b * 16 + nt) * 2) * 1024 + j0 + tid;
        part[base] = m;
        part[base + 1024] = s;
    }
}

__global__ __launch_bounds__(256) void freduce_kernel(const float* __restrict__ part,
                                                      float* __restrict__ out) {
    int t = blockIdx.x * 256 + threadIdx.x;
    if (t >= 8 * 1024) return;
    int b = t >> 10, o = t & 1023;
    float m = -INFINITY, s = 0.f;
#pragma unroll
    for (int nt = 0; nt < 16; ++nt) {
        size_t base = (size_t)((b * 16 + nt) * 2) * 1024 + o;
        m = fmaxf(m, part[base]);
        s += part[base + 1024];
    }
    out[b * 2048 + o] = m;
    out[b * 2048 + 1024 + o] = s * (1.0f / 2048.0f);
}

// ---------------------------------------------------------------------------
extern "C" void kernel_launch(void* const* d_in, const int* in_sizes, int n_in,
                              void* d_out, int out_size, void* d_ws, size_t ws_size,
                              hipStream_t stream) {
    const float* points = (const float*)d_in[0];
    const float* W1 = (const float*)d_in[1];
    const float* W2 = (const float*)d_in[2];
    const float* W3 = (const float*)d_in[3];
    const float* W4 = (const float*)d_in[4];
    const float* W5 = (const float*)d_in[5];
    const float* g1 = (const float*)d_in[6];
    const float* b1 = (const float*)d_in[7];
    const float* g2 = (const float*)d_in[8];
    const float* b2 = (const float*)d_in[9];
    const float* g3 = (const float*)d_in[10];
    const float* b3 = (const float*)d_in[11];
    const float* g4 = (const float*)d_in[12];
    const float* b4 = (const float*)d_in[13];
    const float* g5 = (const float*)d_in[14];
    const float* b5 = (const float*)d_in[15];
    float* out = (float*)d_out;

    // ---- round-4 memory layout, verbatim ----
    const size_t f_xcat = (size_t)BN_TOTAL * 512;          // 8,388,608 floats
    const size_t f_w5 = (size_t)1024 * 512;                // 524,288 elems
    const size_t f_x2 = BN_TOTAL;
    const size_t f_idx = (size_t)BN_TOTAL * KNN;
    const size_t f_part = (size_t)8 * 16 * 2 * 1024;
    const size_t f_bf16 = f_xcat + f_w5;                   // in float units
    const size_t fixedf = f_xcat + f_x2 + f_idx + f_part + f_bf16;
    auto needB = [&](int c) {
        size_t spq = (size_t)c * NPTS * NPTS;
        if (spq < f_xcat) spq = f_xcat;
        return 4ull * (fixedf + spq);
    };
    int cB = 2;
    if (ws_size >= needB(8)) cB = 8;
    else if (ws_size >= needB(4)) cB = 4;
    size_t spq_f = (size_t)cB * NPTS * NPTS;
    if (spq_f < f_xcat) spq_f = f_xcat;

    float* xcat = (float*)d_ws;
    float* SPQ = xcat + f_xcat;
    float* x2 = SPQ + spq_f;
    int* idx = (int*)(x2 + f_x2);
    float* part = (float*)(idx + f_idx);
    unsigned short* Xhi = (unsigned short*)(part + f_part);
    unsigned short* Xlo = Xhi + f_xcat;
    unsigned short* Whi = Xlo + f_xcat;
    unsigned short* Wlo = Whi + f_w5;

    auto layer = [&](const float* xin, int C, int ldx, const float* W, int O, int oshift,
                     const float* ga, const float* be, float* xout) {
        x2_kernel<<<(BN_TOTAL + 255) / 256, 256, 0, stream>>>(xin, C, ldx, x2);
        for (int b0 = 0; b0 < BATCH; b0 += cB) {
            dist_kernel<<<dim3(16, 16, cB), 256, 0, stream>>>(xin, x2, C, ldx, b0, SPQ);
            topk_kernel<<<cB * 512, 256, 0, stream>>>(SPQ, b0, idx);
        }
        pq_gemm<<<dim3(BN_TOTAL / 64, (2 * O) / 64), 256, 0, stream>>>(xin, C, ldx, W, O, SPQ);
        int rpb = 256 >> oshift;
        gmax_kernel<<<BN_TOTAL / rpb, 256, 0, stream>>>(SPQ, idx, O, oshift, ga, be, xout, 512);
    };

    layer(points,     3,   3,   W1, 64,  6, g1, b1, xcat + 0);
    layer(xcat + 0,   64,  512, W2, 64,  6, g2, b2, xcat + 64);
    layer(xcat + 64,  64,  512, W3, 128, 7, g3, b3, xcat + 128);
    layer(xcat + 128, 128, 512, W4, 256, 8, g4, b4, xcat + 256);

    split_bf16_kernel<<<(int)((f_xcat / 4 + 255) / 256), 256, 0, stream>>>(xcat, (int)(f_xcat / 4), Xhi, Xlo);
    split_bf16_kernel<<<(int)((f_w5 / 4 + 255) / 256), 256, 0, stream>>>(W5, (int)(f_w5 / 4), Whi, Wlo);
    final_mfma<<<dim3(BN_TOTAL / 128, 1024 / 128), 256, 0, stream>>>(Xhi, Xlo, Whi, Wlo, g5, b5, part);
    freduce_kernel<<<(8 * 1024 + 255) / 256, 256, 0, stream>>>(part, out);
}